// Round 26
// baseline (3077.833 us; speedup 1.0000x reference)
//
#include <hip/hip_runtime.h>

#define QS 8
#define KC 1024
#define DD 256
#define TT 8192
#define NN 65536
#define TAU 0.06f

typedef _Float16 half8 __attribute__((ext_vector_type(8)));
typedef float f32x4 __attribute__((ext_vector_type(4)));

// ---------------------------------------------------------------------------
// All-stage codebook prep, FRAGMENT-LINEAR (proven layout), per stage:
// tile t = cg*4+kp; fragment f = kc2*4+nt; lane l slot at t*4096 + f*512 + l*8.
// ---------------------------------------------------------------------------
__global__ __launch_bounds__(256) void cb_prep_all_kernel(
    const float* __restrict__ cbs, _Float16* __restrict__ cbh)
{
    const int b = blockIdx.x, s = b >> 6, t = b & 63;   // grid = QS*64
    const int cg = t >> 2, kp = t & 3;
    const float* cb = cbs + (size_t)s * KC * DD;
    _Float16* dst = cbh + (size_t)s * KC * DD + (size_t)t * 4096;
    #pragma unroll
    for (int q = 0; q < 2; ++q) {
        const int p = threadIdx.x + 256*q;      // chunk in [0,512)
        const int kc2 = p >> 8, rem = p & 255;
        const int nt = rem >> 6, l4v = (rem >> 4) & 3, l15v = rem & 15;
        const int code = cg*64 + nt*16 + l15v;
        const int k0 = kp*64 + kc2*32 + l4v*8;
        const float* src = &cb[(long)code*DD + k0];
        const float4 v0 = *reinterpret_cast<const float4*>(src);
        const float4 v1 = *reinterpret_cast<const float4*>(src + 4);
        half8 hv;
        hv[0]=(_Float16)v0.x; hv[1]=(_Float16)v0.y;
        hv[2]=(_Float16)v0.z; hv[3]=(_Float16)v0.w;
        hv[4]=(_Float16)v1.x; hv[5]=(_Float16)v1.y;
        hv[6]=(_Float16)v1.z; hv[7]=(_Float16)v1.w;
        *reinterpret_cast<half8*>(
            &dst[(kc2*4 + nt)*512 + (l4v*16 + l15v)*8]) = hv;
    }
}

// ---------------------------------------------------------------------------
// c2[s][k] = ||codebook[s][k]||^2 ; also zeroes lossAcc (before mega).
// ---------------------------------------------------------------------------
__global__ __launch_bounds__(256) void c2_kernel(
    const float* __restrict__ cbs, float* __restrict__ c2,
    float* __restrict__ lossAcc)
{
    if (blockIdx.x == 0 && threadIdx.x == 0) *lossAcc = 0.0f;
    const int w = (int)((blockIdx.x * blockDim.x + threadIdx.x) >> 6);
    const int lane = threadIdx.x & 63;
    if (w >= QS * KC) return;
    const float* row = cbs + (long)w * DD;
    float s = 0.0f;
    #pragma unroll
    for (int q = 0; q < DD / 64; ++q) {
        const float v = row[lane + 64*q];
        s += v * v;
    }
    #pragma unroll
    for (int off = 32; off; off >>= 1) s += __shfl_down(s, off, 64);
    if (lane == 0) c2[w] = s;
}

// ---------------------------------------------------------------------------
// MEGA v8b — CODE-SPLIT (R25) + RACE FIX: 64-token blocks (grid 1024),
// 512 thr = 8 waves = 4 token-groups x 2 code-halves -> 8192 waves total
// (8/SIMD vs the 4/SIMD structural cap of the unsplit form).
// R25's bug: in the update phase, h=0 overwrote the shared al in LDS while
// h=1 was still reading it. Fix: BOTH halves stage old al into regs
// (alold[8]) -> __syncthreads -> update from alold, h=0 writes new al.
// ---------------------------------------------------------------------------
__global__ __launch_bounds__(512, 8) void mega_kernel(
    const float* __restrict__ x,   const float* __restrict__ ew,
    const float* __restrict__ eb,  const float* __restrict__ cbs,
    const _Float16* __restrict__ cbh, const float* __restrict__ c2all,
    _Float16* __restrict__ resf,   float* __restrict__ lossAcc)
{
    __shared__ __align__(16) _Float16 alds[4 * 8 * 64 * 8];   // 32 KB
    __shared__ int   idxArr[64];
    __shared__ float rrow[DD];
    __shared__ float sD8[8];
    __shared__ int   sI8[8];
    __shared__ int   flagRows[64];
    __shared__ int   flagCnt;
    __shared__ float mD1[64], mD2[64];
    __shared__ int   mI[64];

    const int tid = threadIdx.x;
    const int w   = tid >> 6;          // 0..7
    const int g   = w & 3;             // token group (16 tokens each)
    const int h   = w >> 2;            // code half (0: codes 0-511, 1: 512-1023)
    const int l   = tid & 63;
    const int l15 = l & 15;
    const int l4  = l >> 4;
    const int n0  = blockIdx.x * 64;
    const int n   = n0 + g*16 + l15;   // this lane's token

    // ---- orientation probe (exact; proven rounds 5-24) ----
    int tr;
    {
        half8 pa, pb;
        #pragma unroll
        for (int e = 0; e < 8; ++e) {
            pa[e] = (_Float16)l15;
            pb[e] = (_Float16)0.03125f;
        }
        f32x4 pacc = (f32x4){0.f, 0.f, 0.f, 0.f};
        pacc = __builtin_amdgcn_mfma_f32_16x16x32_f16(pa, pb, pacc, 0, 0, 0);
        const float p1 = __shfl(pacc[1], 0, 64);
        tr = (p1 < 0.5f) ? 1 : 0;
    }

    // ---- fused encoder -> ah (regs, both halves) + al (LDS, h==0 writes) ----
    half8 ah[8];
    {
        const int t = n & (TT - 1);
        const float xm = (t > 0)      ? x[n - 1] : 0.0f;
        const float x0v = x[n];
        const float xp = (t < TT - 1) ? x[n + 1] : 0.0f;
        #pragma unroll
        for (int kc = 0; kc < 8; ++kc) {
            half8 hv, lv;
            #pragma unroll
            for (int e = 0; e < 8; ++e) {
                const int d = kc*32 + l4*8 + e;
                const float z = eb[d] + ew[3*d]*xm + ew[3*d+1]*x0v + ew[3*d+2]*xp;
                const _Float16 hh = (_Float16)z;
                hv[e] = hh;
                lv[e] = (_Float16)(z - (float)hh);
            }
            ah[kc] = hv;
            if (h == 0)
                *reinterpret_cast<half8*>(&alds[((g*8 + kc)*64 + l)*8]) = lv;
        }
    }
    __syncthreads();   // al visible to both halves

    float lsum = 0.0f;

    for (int s = 0; s < QS; ++s) {
        const _Float16* cbhL = cbh + (size_t)s * KC * DD + l*8;
        const float*    cbS  = cbs + (size_t)s * KC * DD;
        const float*    c2S  = c2all + s * KC;

        float b1[4], b2[4]; int i1[4];
        #pragma unroll
        for (int r = 0; r < 4; ++r) { b1[r] = 1e30f; b2[r] = 1e30f; i1[r] = 0; }

        f32x4 acc[4];
        half8 bA[4];

        for (int cgi = 0; cgi < 8; ++cgi) {
            const int cg = h*8 + cgi;          // absolute code group
            #pragma unroll
            for (int nt = 0; nt < 4; ++nt) acc[nt] = (f32x4){0.f,0.f,0.f,0.f};

            for (int kp = 0; kp < 4; ++kp) {
                const _Float16* base = cbhL + (long)(cg*4 + kp)*4096;
                #pragma unroll
                for (int kc2 = 0; kc2 < 2; ++kc2) {
                    const int kc = kp*2 + kc2;
                    const half8 alv = *reinterpret_cast<const half8*>(
                        &alds[((g*8 + kc)*64 + l)*8]);
                    #pragma unroll
                    for (int f = 0; f < 4; ++f)
                        bA[f] = *reinterpret_cast<const half8*>(base + (kc2*4 + f)*512);
                    #pragma unroll
                    for (int nt = 0; nt < 4; ++nt) {
                        acc[nt] = __builtin_amdgcn_mfma_f32_16x16x32_f16(ah[kc], bA[nt], acc[nt], 0, 0, 0);
                        acc[nt] = __builtin_amdgcn_mfma_f32_16x16x32_f16(alv,    bA[nt], acc[nt], 0, 0, 0);
                    }
                }
            }

            if (tr == 0) {
                // token on reg side (row=l4*4+j), code on lane side (col=l15)
                #pragma unroll
                for (int nt = 0; nt < 4; ++nt) {
                    const int code = cg*64 + nt*16 + l15;
                    const float cc = c2S[code];
                    #pragma unroll
                    for (int j = 0; j < 4; ++j) {
                        const float dist = fmaf(-2.0f, acc[nt][j], cc);
                        const bool lt = dist < b1[j];
                        b2[j] = fminf(b2[j], fmaxf(b1[j], dist));
                        b1[j] = lt ? dist : b1[j];
                        i1[j] = lt ? code : i1[j];
                    }
                }
            } else {
                // token on lane side (l15), code on reg side (l4*4+j)
                #pragma unroll
                for (int nt = 0; nt < 4; ++nt) {
                    #pragma unroll
                    for (int j = 0; j < 4; ++j) {
                        const int code = cg*64 + nt*16 + l4*4 + j;
                        const float dist = fmaf(-2.0f, acc[nt][j], c2S[code]);
                        const bool lt = dist < b1[0];
                        b2[0] = fminf(b2[0], fmaxf(b1[0], dist));
                        b1[0] = lt ? dist : b1[0];
                        i1[0] = lt ? code : i1[0];
                    }
                }
            }
        }

        // ---- flag-count reset with explicit ordering ----
        __syncthreads();                       // A: prev-phase LDS consumers done
        if (tid == 0) flagCnt = 0;
        __syncthreads();                       // B: reset visible

        // ---- intra-wave reduce (per half) ----
        if (tr == 0) {
            #pragma unroll
            for (int m = 1; m < 16; m <<= 1) {
                #pragma unroll
                for (int r = 0; r < 4; ++r) {
                    const float ob1 = __shfl_xor(b1[r], m, 64);
                    const float ob2 = __shfl_xor(b2[r], m, 64);
                    const int   oi1 = __shfl_xor(i1[r], m, 64);
                    const float nb2 = fminf(fminf(b2[r], ob2), fmaxf(b1[r], ob1));
                    if (ob1 < b1[r] || (ob1 == b1[r] && oi1 < i1[r])) { b1[r] = ob1; i1[r] = oi1; }
                    b2[r] = nb2;
                }
            }
            if (h == 1 && l15 == 0) {
                #pragma unroll
                for (int j = 0; j < 4; ++j) {
                    const int row = g*16 + l4*4 + j;
                    mD1[row] = b1[j]; mD2[row] = b2[j]; mI[row] = i1[j];
                }
            }
        } else {
            #pragma unroll
            for (int m = 16; m <= 32; m <<= 1) {
                const float ob1 = __shfl_xor(b1[0], m, 64);
                const float ob2 = __shfl_xor(b2[0], m, 64);
                const int   oi1 = __shfl_xor(i1[0], m, 64);
                const float nb2 = fminf(fminf(b2[0], ob2), fmaxf(b1[0], ob1));
                if (ob1 < b1[0] || (ob1 == b1[0] && oi1 < i1[0])) { b1[0] = ob1; i1[0] = oi1; }
                b2[0] = nb2;
            }
            if (h == 1 && l4 == 0) {
                const int row = g*16 + l15;
                mD1[row] = b1[0]; mD2[row] = b2[0]; mI[row] = i1[0];
            }
        }
        __syncthreads();                       // D: half-1 candidates visible

        // ---- half-0 merges pair -> idxArr + flags ----
        // (half-0 codes < half-1 codes, so tie -> half-0 = exact first-min)
        if (tr == 0) {
            if (h == 0 && l15 == 0) {
                #pragma unroll
                for (int j = 0; j < 4; ++j) {
                    const int row = g*16 + l4*4 + j;
                    const float d1b = mD1[row], d2b = mD2[row];
                    const int   ib  = mI[row];
                    const float nb2 = fminf(fminf(b2[j], d2b), fmaxf(b1[j], d1b));
                    float nb1; int ni;
                    if (d1b < b1[j]) { nb1 = d1b; ni = ib; }
                    else             { nb1 = b1[j]; ni = i1[j]; }
                    idxArr[row] = ni;
                    if (nb2 - nb1 < TAU) {
                        const int pos = atomicAdd(&flagCnt, 1);
                        flagRows[pos] = row;
                    }
                }
            }
        } else {
            if (h == 0 && l4 == 0) {
                const int row = g*16 + l15;
                const float d1b = mD1[row], d2b = mD2[row];
                const int   ib  = mI[row];
                const float nb2 = fminf(fminf(b2[0], d2b), fmaxf(b1[0], d1b));
                float nb1; int ni;
                if (d1b < b1[0]) { nb1 = d1b; ni = ib; }
                else             { nb1 = b1[0]; ni = i1[0]; }
                idxArr[row] = ni;
                if (nb2 - nb1 < TAU) {
                    const int pos = atomicAdd(&flagCnt, 1);
                    flagRows[pos] = row;
                }
            }
        }
        __syncthreads();                       // C: idxArr + flags visible

        // ---- inline exact recheck (pre-update residual from ah + alds) ----
        const int fc = flagCnt;
        for (int f = 0; f < fc; ++f) {
            const int row = flagRows[f];
            if (h == 0 && g == (row >> 4) && l15 == (row & 15)) {
                #pragma unroll
                for (int kc = 0; kc < 8; ++kc) {
                    const half8 alv = *reinterpret_cast<const half8*>(
                        &alds[((g*8 + kc)*64 + l)*8]);
                    #pragma unroll
                    for (int e = 0; e < 8; ++e)
                        rrow[kc*32 + l4*8 + e] = (float)ah[kc][e] + (float)alv[e];
                }
            }
            __syncthreads();
            float bd = 1e30f; int bi = 0;
            #pragma unroll
            for (int q = 0; q < 2; ++q) {
                const int code = tid*2 + q;
                const float* crow = cbS + (size_t)code * DD;
                float dot = 0.f;
                for (int d4 = 0; d4 < DD; d4 += 4) {
                    const float4 cv = *reinterpret_cast<const float4*>(&crow[d4]);
                    dot += rrow[d4]*cv.x + rrow[d4+1]*cv.y
                         + rrow[d4+2]*cv.z + rrow[d4+3]*cv.w;
                }
                const float dist = c2S[code] - 2.0f*dot;
                if (dist < bd || (dist == bd && code < bi)) { bd = dist; bi = code; }
            }
            #pragma unroll
            for (int off = 32; off; off >>= 1) {
                const float od = __shfl_down(bd, off, 64);
                const int   oi = __shfl_down(bi, off, 64);
                if (od < bd || (od == bd && oi < bi)) { bd = od; bi = oi; }
            }
            if (l == 0) { sD8[w] = bd; sI8[w] = bi; }
            __syncthreads();
            if (tid == 0) {
                float fbd = sD8[0]; int fbi = sI8[0];
                #pragma unroll
                for (int ww = 1; ww < 8; ++ww) {
                    if (sD8[ww] < fbd || (sD8[ww] == fbd && sI8[ww] < fbi)) {
                        fbd = sD8[ww]; fbi = sI8[ww];
                    }
                }
                idxArr[row] = fbi;
            }
            __syncthreads();
        }

        // ---- TWO-PHASE residual update (RACE FIX) ----
        // Phase 1: BOTH halves stage old al into regs.
        half8 alold[8];
        #pragma unroll
        for (int kc = 0; kc < 8; ++kc)
            alold[kc] = *reinterpret_cast<const half8*>(
                &alds[((g*8 + kc)*64 + l)*8]);
        __syncthreads();                       // all reads done before overwrite

        // Phase 2: update from alold; h==0 writes new al + accumulates loss.
        const int ix = idxArr[g*16 + l15];
        const float* crow = cbS + (size_t)ix * DD;
        #pragma unroll
        for (int kc = 0; kc < 8; ++kc) {
            const float4 c0 = *reinterpret_cast<const float4*>(&crow[kc*32 + l4*8]);
            const float4 c1 = *reinterpret_cast<const float4*>(&crow[kc*32 + l4*8 + 4]);
            const float cv[8] = {c0.x, c0.y, c0.z, c0.w, c1.x, c1.y, c1.z, c1.w};
            half8 hv, lv;
            #pragma unroll
            for (int e = 0; e < 8; ++e) {
                const float rv = ((float)ah[kc][e] + (float)alold[kc][e]) - cv[e];
                if (h == 0) lsum += rv * rv;
                const _Float16 hh = (_Float16)rv;
                hv[e] = hh;
                lv[e] = (_Float16)(rv - (float)hh);
            }
            ah[kc] = hv;
            if (h == 0)
                *reinterpret_cast<half8*>(&alds[((g*8 + kc)*64 + l)*8]) = lv;
        }
        __syncthreads();                       // E: new al visible before next K-loop
    }

    // ---- store final residual (f16, token-major) + loss (h==0 only) ----
    if (h == 0) {
        #pragma unroll
        for (int kc = 0; kc < 8; ++kc) {
            const half8 alv = *reinterpret_cast<const half8*>(
                &alds[((g*8 + kc)*64 + l)*8]);
            half8 hv;
            #pragma unroll
            for (int e = 0; e < 8; ++e)
                hv[e] = (_Float16)((float)ah[kc][e] + (float)alv[e]);
            *reinterpret_cast<half8*>(&resf[(size_t)n*DD + kc*32 + l4*8]) = hv;
        }
        #pragma unroll
        for (int off = 32; off; off >>= 1) lsum += __shfl_down(lsum, off, 64);
        if (l == 0) atomicAdd(lossAcc, lsum);
    }
}

// ---------------------------------------------------------------------------
// Decoder: quant = z - res_final (z recomputed; res f16); conv1d + loss out.
// ---------------------------------------------------------------------------
__global__ __launch_bounds__(256) void decode_kernel(
    const float* __restrict__ x,  const float* __restrict__ ew,
    const float* __restrict__ eb, const _Float16* __restrict__ resf,
    const float* __restrict__ dw, const float* __restrict__ db,
    const float* __restrict__ lossAcc, float* __restrict__ out)
{
    const long n = (long)blockIdx.x * 4 + (threadIdx.x >> 6);
    const int lane = threadIdx.x & 63;
    const int t = (int)(n & (TT - 1));
    float sum = 0.0f;
    #pragma unroll
    for (int k = 0; k < 3; ++k) {
        const int tm = t + k - 1;
        if (tm < 0 || tm > TT - 1) continue;
        const long m = n + k - 1;
        const float xm = (tm > 0)      ? x[m - 1] : 0.0f;
        const float x0 = x[m];
        const float xp = (tm < TT - 1) ? x[m + 1] : 0.0f;
        #pragma unroll
        for (int q = 0; q < 4; ++q) {
            const int d = lane + 64 * q;
            const float z = eb[d] + ew[d*3]*xm + ew[d*3 + 1]*x0 + ew[d*3 + 2]*xp;
            const float quant = z - (float)resf[m * DD + d];
            sum += quant * dw[d*3 + k];
        }
    }
    #pragma unroll
    for (int off = 32; off; off >>= 1) sum += __shfl_down(sum, off, 64);
    if (lane == 0) out[n] = sum + db[0];
    if (blockIdx.x == 0 && threadIdx.x == 0)
        out[NN] = lossAcc[0] * (1.0f / ((float)NN * (float)DD));
}

// ---------------------------------------------------------------------------
// Workspace: d_ws = resf16 32MB + cbh 4MB + lossAcc (~36MB, proven-safe).
// d_out scratch until decode: [8..8199] = c2 (consumed by mega before decode).
// ---------------------------------------------------------------------------
extern "C" void kernel_launch(void* const* d_in, const int* in_sizes, int n_in,
                              void* d_out, int out_size, void* d_ws, size_t ws_size,
                              hipStream_t stream)
{
    const float* x     = (const float*)d_in[0];
    const float* enc_w = (const float*)d_in[1];
    const float* enc_b = (const float*)d_in[2];
    const float* dec_w = (const float*)d_in[3];
    const float* dec_b = (const float*)d_in[4];
    const float* cbs   = (const float*)d_in[5];
    float* out = (float*)d_out;

    _Float16* resf    = (_Float16*)d_ws;                 // [NN][DD] f16 = 32 MB
    _Float16* cbh     = resf + (size_t)NN * DD;          // [QS][KC][DD] f16 = 4 MB
    float*    lossAcc = (float*)(cbh + (size_t)QS * KC * DD);
    float*    c2      = out + 8;                         // [QS*KC] in d_out

    hipLaunchKernelGGL(cb_prep_all_kernel, dim3(QS * 64), dim3(256), 0, stream,
                       cbs, cbh);
    hipLaunchKernelGGL(c2_kernel, dim3(QS * KC / 4), dim3(256), 0, stream,
                       cbs, c2, lossAcc);
    hipLaunchKernelGGL(mega_kernel, dim3(NN / 64), dim3(512), 0, stream,
                       x, enc_w, enc_b, cbs, cbh, c2, resf, lossAcc);
    hipLaunchKernelGGL(decode_kernel, dim3(NN / 4), dim3(256), 0, stream,
                       x, enc_w, enc_b, resf, dec_w, dec_b, lossAcc, out);
}

// Round 27
// 1232.409 us; speedup vs baseline: 2.4974x; 2.4974x over previous
//
#include <hip/hip_runtime.h>

#define QS 8
#define KC 1024
#define DD 256
#define TT 8192
#define NN 65536
#define TAU 0.06f

typedef _Float16 half8 __attribute__((ext_vector_type(8)));
typedef float f32x4 __attribute__((ext_vector_type(4)));

// ---------------------------------------------------------------------------
// All-stage codebook prep, FRAGMENT-LINEAR (proven layout), per stage:
// tile t = cg*4+kp; fragment f = kc2*4+nt; lane l slot at t*4096 + f*512 + l*8.
// ---------------------------------------------------------------------------
__global__ __launch_bounds__(256) void cb_prep_all_kernel(
    const float* __restrict__ cbs, _Float16* __restrict__ cbh)
{
    const int b = blockIdx.x, s = b >> 6, t = b & 63;   // grid = QS*64
    const int cg = t >> 2, kp = t & 3;
    const float* cb = cbs + (size_t)s * KC * DD;
    _Float16* dst = cbh + (size_t)s * KC * DD + (size_t)t * 4096;
    #pragma unroll
    for (int q = 0; q < 2; ++q) {
        const int p = threadIdx.x + 256*q;      // chunk in [0,512)
        const int kc2 = p >> 8, rem = p & 255;
        const int nt = rem >> 6, l4v = (rem >> 4) & 3, l15v = rem & 15;
        const int code = cg*64 + nt*16 + l15v;
        const int k0 = kp*64 + kc2*32 + l4v*8;
        const float* src = &cb[(long)code*DD + k0];
        const float4 v0 = *reinterpret_cast<const float4*>(src);
        const float4 v1 = *reinterpret_cast<const float4*>(src + 4);
        half8 hv;
        hv[0]=(_Float16)v0.x; hv[1]=(_Float16)v0.y;
        hv[2]=(_Float16)v0.z; hv[3]=(_Float16)v0.w;
        hv[4]=(_Float16)v1.x; hv[5]=(_Float16)v1.y;
        hv[6]=(_Float16)v1.z; hv[7]=(_Float16)v1.w;
        *reinterpret_cast<half8*>(
            &dst[(kc2*4 + nt)*512 + (l4v*16 + l15v)*8]) = hv;
    }
}

// ---------------------------------------------------------------------------
// c2[s][k] = ||codebook[s][k]||^2 ; also zeroes lossAcc (before mega).
// ---------------------------------------------------------------------------
__global__ __launch_bounds__(256) void c2_kernel(
    const float* __restrict__ cbs, float* __restrict__ c2,
    float* __restrict__ lossAcc)
{
    if (blockIdx.x == 0 && threadIdx.x == 0) *lossAcc = 0.0f;
    const int w = (int)((blockIdx.x * blockDim.x + threadIdx.x) >> 6);
    const int lane = threadIdx.x & 63;
    if (w >= QS * KC) return;
    const float* row = cbs + (long)w * DD;
    float s = 0.0f;
    #pragma unroll
    for (int q = 0; q < DD / 64; ++q) {
        const float v = row[lane + 64*q];
        s += v * v;
    }
    #pragma unroll
    for (int off = 32; off; off >>= 1) s += __shfl_down(s, off, 64);
    if (lane == 0) c2[w] = s;
}

// ---------------------------------------------------------------------------
// MEGA v6 (R22/R24 — the proven best, reproduced at 1237/1235 us total):
// encode + 8 fused RVQ stages. 512 thr (8 waves), wave owns 16 tokens
// (block = 128 tokens, grid = 512). __launch_bounds__(512, 4):
//   - al (f16 lo-half residual) in EXPLICIT LDS alds[8][512] (64 KB,
//     own-slot access -> conflict-free ds_read_b128)
//   - ah in regs; allocator spills ~0.6 GB (hidden by TLP; measured cheaper
//     than occupancy loss of keeping it)
//   - occupancy 34% = 4 waves/SIMD, the structural cap (65536 tok / 16 per
//     wave = 4096 waves). Config map: (512,4)=1270 beats (256,3)=1630,
//     (256,-)=2890, (256,8)=2920, (512,3)=1520, code-split(512,8)=3130.
// Per stage: streaming barrier-free K-loop (B from L2, fragment-linear) ->
// lean fold -> barriered flags -> inline exact fp32 recheck ->
// register update + resplit. Zero inter-stage HBM traffic.
// ---------------------------------------------------------------------------
__global__ __launch_bounds__(512, 4) void mega_kernel(
    const float* __restrict__ x,   const float* __restrict__ ew,
    const float* __restrict__ eb,  const float* __restrict__ cbs,
    const _Float16* __restrict__ cbh, const float* __restrict__ c2all,
    _Float16* __restrict__ resf,   float* __restrict__ lossAcc)
{
    __shared__ __align__(16) _Float16 alds[8 * 512 * 8];   // 64 KB
    __shared__ int   idxArr[128];
    __shared__ float rrow[DD];
    __shared__ float sD8[8];
    __shared__ int   sI8[8];
    __shared__ int   flagRows[128];
    __shared__ int   flagCnt;

    const int tid = threadIdx.x;
    const int w   = tid >> 6;          // 0..7
    const int l   = tid & 63;
    const int l15 = l & 15;
    const int l4  = l >> 4;
    const int n0  = blockIdx.x * 128;
    const int n   = n0 + w*16 + l15;   // this lane's token

    // ---- orientation probe (exact; proven rounds 5-26) ----
    int tr;
    {
        half8 pa, pb;
        #pragma unroll
        for (int e = 0; e < 8; ++e) {
            pa[e] = (_Float16)l15;
            pb[e] = (_Float16)0.03125f;
        }
        f32x4 pacc = (f32x4){0.f, 0.f, 0.f, 0.f};
        pacc = __builtin_amdgcn_mfma_f32_16x16x32_f16(pa, pb, pacc, 0, 0, 0);
        const float p1 = __shfl(pacc[1], 0, 64);
        tr = (p1 < 0.5f) ? 1 : 0;
    }

    // ---- fused encoder -> ah (regs) + al (LDS) ----
    half8 ah[8];
    {
        const int t = n & (TT - 1);
        const float xm = (t > 0)      ? x[n - 1] : 0.0f;
        const float x0v = x[n];
        const float xp = (t < TT - 1) ? x[n + 1] : 0.0f;
        #pragma unroll
        for (int kc = 0; kc < 8; ++kc) {
            half8 hv, lv;
            #pragma unroll
            for (int e = 0; e < 8; ++e) {
                const int d = kc*32 + l4*8 + e;
                const float z = eb[d] + ew[3*d]*xm + ew[3*d+1]*x0v + ew[3*d+2]*xp;
                const _Float16 hh = (_Float16)z;
                hv[e] = hh;
                lv[e] = (_Float16)(z - (float)hh);
            }
            ah[kc] = hv;
            *reinterpret_cast<half8*>(&alds[(kc*512 + tid)*8]) = lv;
        }
    }

    float lsum = 0.0f;

    for (int s = 0; s < QS; ++s) {
        const _Float16* cbhL = cbh + (size_t)s * KC * DD + l*8;
        const float*    cbS  = cbs + (size_t)s * KC * DD;
        const float*    c2S  = c2all + s * KC;

        float b1[4], b2[4]; int i1[4];
        #pragma unroll
        for (int r = 0; r < 4; ++r) { b1[r] = 1e30f; b2[r] = 1e30f; i1[r] = 0; }

        f32x4 acc[4];
        half8 bA[4];

        for (int cg = 0; cg < 16; ++cg) {
            #pragma unroll
            for (int nt = 0; nt < 4; ++nt) acc[nt] = (f32x4){0.f,0.f,0.f,0.f};

            for (int kp = 0; kp < 4; ++kp) {
                const _Float16* base = cbhL + (long)(cg*4 + kp)*4096;
                #pragma unroll
                for (int kc2 = 0; kc2 < 2; ++kc2) {
                    const int kc = kp*2 + kc2;
                    const half8 alv = *reinterpret_cast<const half8*>(
                        &alds[(kc*512 + tid)*8]);
                    #pragma unroll
                    for (int f = 0; f < 4; ++f)
                        bA[f] = *reinterpret_cast<const half8*>(base + (kc2*4 + f)*512);
                    #pragma unroll
                    for (int nt = 0; nt < 4; ++nt) {
                        acc[nt] = __builtin_amdgcn_mfma_f32_16x16x32_f16(ah[kc], bA[nt], acc[nt], 0, 0, 0);
                        acc[nt] = __builtin_amdgcn_mfma_f32_16x16x32_f16(alv,    bA[nt], acc[nt], 0, 0, 0);
                    }
                }
            }

            if (tr == 0) {
                // token on reg side (row=l4*4+j), code on lane side (col=l15)
                #pragma unroll
                for (int nt = 0; nt < 4; ++nt) {
                    const int code = cg*64 + nt*16 + l15;
                    const float cc = c2S[code];
                    #pragma unroll
                    for (int j = 0; j < 4; ++j) {
                        const float dist = fmaf(-2.0f, acc[nt][j], cc);
                        const bool lt = dist < b1[j];
                        b2[j] = fminf(b2[j], fmaxf(b1[j], dist));
                        b1[j] = lt ? dist : b1[j];
                        i1[j] = lt ? code : i1[j];
                    }
                }
            } else {
                // token on lane side (l15), code on reg side (l4*4+j)
                #pragma unroll
                for (int nt = 0; nt < 4; ++nt) {
                    #pragma unroll
                    for (int j = 0; j < 4; ++j) {
                        const int code = cg*64 + nt*16 + l4*4 + j;
                        const float dist = fmaf(-2.0f, acc[nt][j], c2S[code]);
                        const bool lt = dist < b1[0];
                        b2[0] = fminf(b2[0], fmaxf(b1[0], dist));
                        b1[0] = lt ? dist : b1[0];
                        i1[0] = lt ? code : i1[0];
                    }
                }
            }
        }

        // ---- flag-count reset with explicit ordering ----
        __syncthreads();                       // A: prev-stage LDS consumers done
        if (tid == 0) flagCnt = 0;
        __syncthreads();                       // B: reset visible

        // ---- cross-lane reduce + idxArr + flags ----
        if (tr == 0) {
            #pragma unroll
            for (int m = 1; m < 16; m <<= 1) {
                #pragma unroll
                for (int r = 0; r < 4; ++r) {
                    const float ob1 = __shfl_xor(b1[r], m, 64);
                    const float ob2 = __shfl_xor(b2[r], m, 64);
                    const int   oi1 = __shfl_xor(i1[r], m, 64);
                    const float nb2 = fminf(fminf(b2[r], ob2), fmaxf(b1[r], ob1));
                    if (ob1 < b1[r] || (ob1 == b1[r] && oi1 < i1[r])) { b1[r] = ob1; i1[r] = oi1; }
                    b2[r] = nb2;
                }
            }
            if (l15 == 0) {
                #pragma unroll
                for (int j = 0; j < 4; ++j) {
                    const int row = w*16 + l4*4 + j;
                    idxArr[row] = i1[j];
                    if (b2[j] - b1[j] < TAU) {
                        const int pos = atomicAdd(&flagCnt, 1);
                        flagRows[pos] = row;            // cap 128 = all rows
                    }
                }
            }
        } else {
            #pragma unroll
            for (int m = 16; m <= 32; m <<= 1) {
                const float ob1 = __shfl_xor(b1[0], m, 64);
                const float ob2 = __shfl_xor(b2[0], m, 64);
                const int   oi1 = __shfl_xor(i1[0], m, 64);
                const float nb2 = fminf(fminf(b2[0], ob2), fmaxf(b1[0], ob1));
                if (ob1 < b1[0] || (ob1 == b1[0] && oi1 < i1[0])) { b1[0] = ob1; i1[0] = oi1; }
                b2[0] = nb2;
            }
            if (l4 == 0) {
                const int row = w*16 + l15;
                idxArr[row] = i1[0];
                if (b2[0] - b1[0] < TAU) {
                    const int pos = atomicAdd(&flagCnt, 1);
                    flagRows[pos] = row;
                }
            }
        }
        __syncthreads();                       // C: idxArr + flags visible

        // ---- inline exact recheck (pre-update residual from ah + alds) ----
        const int fc = flagCnt;
        for (int f = 0; f < fc; ++f) {
            const int row = flagRows[f];
            if (w == (row >> 4) && l15 == (row & 15)) {
                #pragma unroll
                for (int kc = 0; kc < 8; ++kc) {
                    const half8 alv = *reinterpret_cast<const half8*>(
                        &alds[(kc*512 + tid)*8]);
                    #pragma unroll
                    for (int e = 0; e < 8; ++e)
                        rrow[kc*32 + l4*8 + e] = (float)ah[kc][e] + (float)alv[e];
                }
            }
            __syncthreads();
            float bd = 1e30f; int bi = 0;
            #pragma unroll
            for (int q = 0; q < 2; ++q) {
                const int code = tid*2 + q;
                const float* crow = cbS + (size_t)code * DD;
                float dot = 0.f;
                for (int d4 = 0; d4 < DD; d4 += 4) {
                    const float4 cv = *reinterpret_cast<const float4*>(&crow[d4]);
                    dot += rrow[d4]*cv.x + rrow[d4+1]*cv.y
                         + rrow[d4+2]*cv.z + rrow[d4+3]*cv.w;
                }
                const float dist = c2S[code] - 2.0f*dot;
                if (dist < bd || (dist == bd && code < bi)) { bd = dist; bi = code; }
            }
            #pragma unroll
            for (int off = 32; off; off >>= 1) {
                const float od = __shfl_down(bd, off, 64);
                const int   oi = __shfl_down(bi, off, 64);
                if (od < bd || (od == bd && oi < bi)) { bd = od; bi = oi; }
            }
            if (l == 0) { sD8[w] = bd; sI8[w] = bi; }
            __syncthreads();
            if (tid == 0) {
                float fbd = sD8[0]; int fbi = sI8[0];
                #pragma unroll
                for (int ww = 1; ww < 8; ++ww) {
                    if (sD8[ww] < fbd || (sD8[ww] == fbd && sI8[ww] < fbi)) {
                        fbd = sD8[ww]; fbi = sI8[ww];
                    }
                }
                idxArr[row] = fbi;
            }
            __syncthreads();
        }

        // ---- register residual update (fp32 cb gather) + loss + resplit ----
        const int ix = idxArr[w*16 + l15];
        const float* crow = cbS + (size_t)ix * DD;
        #pragma unroll
        for (int kc = 0; kc < 8; ++kc) {
            const float4 c0 = *reinterpret_cast<const float4*>(&crow[kc*32 + l4*8]);
            const float4 c1 = *reinterpret_cast<const float4*>(&crow[kc*32 + l4*8 + 4]);
            const float cv[8] = {c0.x, c0.y, c0.z, c0.w, c1.x, c1.y, c1.z, c1.w};
            const half8 alv = *reinterpret_cast<const half8*>(
                &alds[(kc*512 + tid)*8]);
            half8 hv, lv;
            #pragma unroll
            for (int e = 0; e < 8; ++e) {
                const float rv = ((float)ah[kc][e] + (float)alv[e]) - cv[e];
                lsum += rv * rv;
                const _Float16 hh = (_Float16)rv;
                hv[e] = hh;
                lv[e] = (_Float16)(rv - (float)hh);
            }
            ah[kc] = hv;
            *reinterpret_cast<half8*>(&alds[(kc*512 + tid)*8]) = lv;
        }
    }

    // ---- store final residual (f16) for decode + loss ----
    #pragma unroll
    for (int kc = 0; kc < 8; ++kc) {
        const half8 alv = *reinterpret_cast<const half8*>(&alds[(kc*512 + tid)*8]);
        half8 hv;
        #pragma unroll
        for (int e = 0; e < 8; ++e)
            hv[e] = (_Float16)((float)ah[kc][e] + (float)alv[e]);
        *reinterpret_cast<half8*>(&resf[(size_t)n*DD + kc*32 + l4*8]) = hv;
    }
    #pragma unroll
    for (int off = 32; off; off >>= 1) lsum += __shfl_down(lsum, off, 64);
    if (l == 0) atomicAdd(lossAcc, lsum);
}

// ---------------------------------------------------------------------------
// Decoder: quant = z - res_final (z recomputed; res f16); conv1d + loss out.
// ---------------------------------------------------------------------------
__global__ __launch_bounds__(256) void decode_kernel(
    const float* __restrict__ x,  const float* __restrict__ ew,
    const float* __restrict__ eb, const _Float16* __restrict__ resf,
    const float* __restrict__ dw, const float* __restrict__ db,
    const float* __restrict__ lossAcc, float* __restrict__ out)
{
    const long n = (long)blockIdx.x * 4 + (threadIdx.x >> 6);
    const int lane = threadIdx.x & 63;
    const int t = (int)(n & (TT - 1));
    float sum = 0.0f;
    #pragma unroll
    for (int k = 0; k < 3; ++k) {
        const int tm = t + k - 1;
        if (tm < 0 || tm > TT - 1) continue;
        const long m = n + k - 1;
        const float xm = (tm > 0)      ? x[m - 1] : 0.0f;
        const float x0 = x[m];
        const float xp = (tm < TT - 1) ? x[m + 1] : 0.0f;
        #pragma unroll
        for (int q = 0; q < 4; ++q) {
            const int d = lane + 64 * q;
            const float z = eb[d] + ew[d*3]*xm + ew[d*3 + 1]*x0 + ew[d*3 + 2]*xp;
            const float quant = z - (float)resf[m * DD + d];
            sum += quant * dw[d*3 + k];
        }
    }
    #pragma unroll
    for (int off = 32; off; off >>= 1) sum += __shfl_down(sum, off, 64);
    if (lane == 0) out[n] = sum + db[0];
    if (blockIdx.x == 0 && threadIdx.x == 0)
        out[NN] = lossAcc[0] * (1.0f / ((float)NN * (float)DD));
}

// ---------------------------------------------------------------------------
// Workspace: d_ws = resf16 32MB + cbh 4MB + lossAcc (~36MB, proven-safe).
// d_out scratch until decode: [8..8199] = c2 (consumed by mega before decode).
// ---------------------------------------------------------------------------
extern "C" void kernel_launch(void* const* d_in, const int* in_sizes, int n_in,
                              void* d_out, int out_size, void* d_ws, size_t ws_size,
                              hipStream_t stream)
{
    const float* x     = (const float*)d_in[0];
    const float* enc_w = (const float*)d_in[1];
    const float* enc_b = (const float*)d_in[2];
    const float* dec_w = (const float*)d_in[3];
    const float* dec_b = (const float*)d_in[4];
    const float* cbs   = (const float*)d_in[5];
    float* out = (float*)d_out;

    _Float16* resf    = (_Float16*)d_ws;                 // [NN][DD] f16 = 32 MB
    _Float16* cbh     = resf + (size_t)NN * DD;          // [QS][KC][DD] f16 = 4 MB
    float*    lossAcc = (float*)(cbh + (size_t)QS * KC * DD);
    float*    c2      = out + 8;                         // [QS*KC] in d_out

    hipLaunchKernelGGL(cb_prep_all_kernel, dim3(QS * 64), dim3(256), 0, stream,
                       cbs, cbh);
    hipLaunchKernelGGL(c2_kernel, dim3(QS * KC / 4), dim3(256), 0, stream,
                       cbs, c2, lossAcc);
    hipLaunchKernelGGL(mega_kernel, dim3(NN / 128), dim3(512), 0, stream,
                       x, enc_w, enc_b, cbs, cbh, c2, resf, lossAcc);
    hipLaunchKernelGGL(decode_kernel, dim3(NN / 4), dim3(256), 0, stream,
                       x, enc_w, enc_b, resf, dec_w, dec_b, lossAcc, out);
}